// Round 4
// baseline (1122.750 us; speedup 1.0000x reference)
//
#include <hip/hip_runtime.h>
#include <hip/hip_bf16.h>
#include <math.h>

#define B_     1024
#define VOCAB_ 130
#define EOS_   129

// Output FLOAT32 element offsets:
//   inv_features @0 (24576) | inv_class_emb @24576 (901120) | str_emb @925696
#define OUT_CLS_F  24576
#define OUT_STR_F  925696

// Workspace (float offsets): POOL 1024*32 | CNT 1024 | HC 1024*16 | T 2*128*48
#define OFF_POOL 0
#define OFF_CNT  32768
#define OFF_HC   33792
#define OFF_T    50176

// merged-grid geometry: 14144 k2-role (14080 GRU + 64 classRNN) 1:1 with 14960 k1-role
#define NK2      14144
#define NK1      14960
#define NINT     28288          // 2 * NK2 interleaved prefix
#define NTOT     29104

typedef float f2 __attribute__((ext_vector_type(2)));

static __device__ const int d_MAP[19] =
    {128,93,41,91,61,34,40,37,33,63,43,47,36,42,96,48,95,46,128};

__device__ __forceinline__ float sigm_(float x){
    return __builtin_amdgcn_rcpf(1.f + __builtin_amdgcn_exp2f(-1.4426950408889634f * x));
}
__device__ __forceinline__ float tanh_(float x){
    return 2.f * __builtin_amdgcn_rcpf(1.f + __builtin_amdgcn_exp2f(-2.8853900817779268f * x)) - 1.f;
}
__device__ __forceinline__ int badf(float v) {
    return (v != v) || (fabsf(v) > 1e30f);
}
__device__ __forceinline__ f2 mkf2(float a, float b){ f2 r; r.x = a; r.y = b; return r; }
// butterfly add with lane^16 partner (within each 32-lane half; BitMode xor=16)
__device__ __forceinline__ float swz16_(float x){
    return __int_as_float(__builtin_amdgcn_ds_swizzle(__float_as_int(x), 0x401F));
}

// ---------------- k0: precompute gi tables T[dir][c][j] = Wih_j . emb[c] + bih[j] (+bhh[j] for j<32)
__global__ void k0_tables(const float* __restrict__ emb,
                          const float* __restrict__ WihF, const float* __restrict__ bihF,
                          const float* __restrict__ bhhF,
                          const float* __restrict__ WihB, const float* __restrict__ bihB,
                          const float* __restrict__ bhhB, float* ws)
{
    int i = blockIdx.x * 256 + threadIdx.x;
    if (i >= 12288) return;                 // 2 * 128 * 48
    int dir = i / 6144, r = i - dir * 6144;
    int c = r / 48, j = r - c * 48;
    const float* Wih = dir ? WihB : WihF;
    const float* bih = dir ? bihB : bihF;
    const float* bhh = dir ? bhhB : bhhF;
    float v = bih[j] + ((j < 32) ? bhh[j] : 0.f);
    if (c != 0) {                           // padding_idx=0 -> emb row 0 is zero
        const float* e = emb + c * 16;
        #pragma unroll
        for (int d = 0; d < 16; ++d) v = fmaf(Wih[j * 16 + d], e[d], v);
    }
    ws[OFF_T + i] = v;
}

// ---------------- k12: merged embed-gather (k1 role) + GRU/RNN (k2 role)
// role: bi<28288: even -> k2(bi/2), odd -> k1(bi/2); bi>=28288 -> k1(14144+bi-28288)
// LDS overlay: k2 uses [0,6272) T-table(pitch49) + [6272,6528) h-exchange
//              k1 uses [0,2600) embF(pitch20)   + [2600,2920) chs
__global__ __launch_bounds__(256)
void k12_main(const int* oclass, const int* strs, const float* __restrict__ emb,
              const float* __restrict__ WhhF, const float* __restrict__ bhhF,
              const float* __restrict__ WhhB, const float* __restrict__ bhhB,
              const float* __restrict__ rWih, const float* __restrict__ rWhh,
              const float* __restrict__ rbih, const float* __restrict__ rbhh,
              float* ws, float* out)
{
    __shared__ __align__(16) float smem[6528];       // 26112 B union
    int bi0 = blockIdx.x, tid = threadIdx.x;

    int k2id = -1, k1id;
    if (bi0 < NINT) {
        if ((bi0 & 1) == 0) k2id = bi0 >> 1;
        else                k1id = bi0 >> 1;
    } else {
        k1id = NK2 + (bi0 - NINT);
    }

    if (k2id < 0) {
        // ================= k1 role: f32 gathers (str_emb + EOS, inv_class_emb)
        float* embF = smem;                          // pitch 20
        int*   chs  = (int*)(smem + 2600);           // 4 * 80
        for (int i = tid; i < VOCAB_ * 16; i += 256) {
            int r = i >> 4, c = i & 15;
            embF[r * 20 + c] = (r == 0) ? 0.f : emb[i];   // padding_idx=0
        }
        __syncthreads();

        if (k1id < 14080) {
            int w = tid >> 6, lane = tid & 63;
            int s = k1id * 4 + w;
            const int* cp = strs + (long)s * 80;
            int ca = cp[lane];
            int cb = (lane < 16) ? cp[64 + lane] : 0;
            unsigned long long m1 = __ballot(ca != 0);
            unsigned long long m2 = __ballot((lane < 16) && (cb != 0));
            int L = __popcll(m1) + __popcll(m2);
            if (lane == L) ca = EOS_;
            if (lane < 16 && (64 + lane) == L) cb = EOS_;
            chs[w * 80 + lane] = ca;                 // wave-local slice: no barrier
            if (lane < 16) chs[w * 80 + 64 + lane] = cb;
            float4* dst = (float4*)(out + OUT_STR_F + (long)s * 1280);
            #pragma unroll
            for (int it = 0; it < 5; ++it) {
                int q = it * 64 + lane;
                int row = q >> 2, part = q & 3;
                int ch = chs[w * 80 + row];
                dst[q] = *(const float4*)&embF[ch * 20 + part * 4];
            }
        } else {
            int q = (k1id - 14080) * 256 + tid;
            int bs = q >> 2, part = q & 3;
            int c = d_MAP[oclass[bs]];
            float4* dst = (float4*)(out + OUT_CLS_F);
            dst[q] = *(const float4*)&embF[c * 20 + part * 4];
        }
        return;
    }

    // ================= k2 role
    float* ldsT = smem;                              // pitch-49 gi-table / pitch-20 T2
    int bi = k2id;

    if (bi < 14080) {
        // ---- GRU: 32 lanes per sequence; lane (p,j): gates for unit j over d in [8p,8p+8)
        int lane = tid & 63;
        int g  = lane >> 5;                          // seq within wave (0,1)
        int q  = lane & 31;
        int p  = q >> 4;                             // d-half
        int j  = q & 15;                             // hidden unit
        int grp8 = ((tid >> 6) << 1) + g;            // seq within block (0..7)
        float* hb = smem + 6272 + grp8 * 16;

        bool fwd = bi < 7040;
        const float* __restrict__ Whh = fwd ? WhhF : WhhB;
        const float* __restrict__ bhh = fwd ? bhhF : bhhB;

        // stage gi-table [128][48] -> LDS pitch 49
        const float* Tg = ws + OFF_T + (fwd ? 0 : 6144);
        for (int i = tid; i < 6144; i += 256) {
            int c = i / 48, qq = i - c * 48;
            ldsT[c * 49 + qq] = Tg[i];
        }

        // 24 weight floats per lane: rows j of Wr/Wz/Wn, d-range [8p, 8p+8)
        f2 wr4[4], wz4[4], wn4[4];
        const float* Wb = Whh + j * 16 + p * 8;
        {
            float4 a0 = *(const float4*)&Wb[0],   a1 = *(const float4*)&Wb[4];
            float4 b0 = *(const float4*)&Wb[256], b1 = *(const float4*)&Wb[260];
            float4 c0 = *(const float4*)&Wb[512], c1 = *(const float4*)&Wb[516];
            wr4[0]=mkf2(a0.x,a0.y); wr4[1]=mkf2(a0.z,a0.w); wr4[2]=mkf2(a1.x,a1.y); wr4[3]=mkf2(a1.z,a1.w);
            wz4[0]=mkf2(b0.x,b0.y); wz4[1]=mkf2(b0.z,b0.w); wz4[2]=mkf2(b1.x,b1.y); wz4[3]=mkf2(b1.z,b1.w);
            wn4[0]=mkf2(c0.x,c0.y); wn4[1]=mkf2(c0.z,c0.w); wn4[2]=mkf2(c1.x,c1.y); wn4[3]=mkf2(c1.z,c1.w);
        }
        #pragma unroll
        for (int k = 0; k < 4; ++k) {
            asm volatile("" : "+v"(wr4[k]));
            asm volatile("" : "+v"(wz4[k]));
            asm volatile("" : "+v"(wn4[k]));
        }
        float bn = bhh[32 + j];
        __syncthreads();

        int s = (fwd ? bi : bi - 7040) * 8 + grp8;
        const int* cp = strs + (long)s * 80;

        // 32-lane length count + swizzle reduce (xor 1,2,4,8,16)
        int cnt = (cp[q] != 0) + (cp[q + 32] != 0);
        if (q < 16) cnt += (cp[q + 64] != 0);
        cnt += __builtin_amdgcn_ds_swizzle(cnt, (1 << 10) | 0x1f);
        cnt += __builtin_amdgcn_ds_swizzle(cnt, (2 << 10) | 0x1f);
        cnt += __builtin_amdgcn_ds_swizzle(cnt, (4 << 10) | 0x1f);
        cnt += __builtin_amdgcn_ds_swizzle(cnt, (8 << 10) | 0x1f);
        cnt += __builtin_amdgcn_ds_swizzle(cnt, (16 << 10) | 0x1f);
        int L = cnt;

        float hj = 0.f;
        hb[j] = 0.f;
        __builtin_amdgcn_wave_barrier();
        if (L > 0) {
            int base = fwd ? 0 : (L - 1);
            int stp  = fwd ? 1 : -1;
            int c  = cp[base];
            int c1 = (L > 1) ? cp[base + stp] : 0;
            for (int t = 0; t < L; ++t) {
                int c2 = (t + 2 < L) ? cp[base + (t + 2) * stp] : 0;  // 2-deep prefetch
                const float* Trow = ldsT + c * 49;
                float t0  = Trow[(p << 4) + j];      // p0: T_r, p1: T_z
                float tn_ = Trow[32 + j];            // T_n (all lanes)
                float4 h0 = *(const float4*)&hb[p * 8];
                float4 h1 = *(const float4*)&hb[p * 8 + 4];
                f2 accr = mkf2(p ? 0.f : t0, 0.f);
                f2 accz = mkf2(p ? t0 : 0.f, 0.f);
                f2 accn = mkf2(p ? 0.f : bn, 0.f);   // T_n kept OUT (r scales only W_n.h + b_n)
                f2 ha = mkf2(h0.x, h0.y), hbv = mkf2(h0.z, h0.w);
                f2 hc = mkf2(h1.x, h1.y), hd  = mkf2(h1.z, h1.w);
                accr = __builtin_elementwise_fma(wr4[0], ha,  accr);
                accz = __builtin_elementwise_fma(wz4[0], ha,  accz);
                accn = __builtin_elementwise_fma(wn4[0], ha,  accn);
                accr = __builtin_elementwise_fma(wr4[1], hbv, accr);
                accz = __builtin_elementwise_fma(wz4[1], hbv, accz);
                accn = __builtin_elementwise_fma(wn4[1], hbv, accn);
                accr = __builtin_elementwise_fma(wr4[2], hc,  accr);
                accz = __builtin_elementwise_fma(wz4[2], hc,  accz);
                accn = __builtin_elementwise_fma(wn4[2], hc,  accn);
                accr = __builtin_elementwise_fma(wr4[3], hd,  accr);
                accz = __builtin_elementwise_fma(wz4[3], hd,  accz);
                accn = __builtin_elementwise_fma(wn4[3], hd,  accn);
                float sr = accr.x + accr.y;
                float sz = accz.x + accz.y;
                float sn = accn.x + accn.y;
                sr += swz16_(sr);                    // full dot at both halves
                sz += swz16_(sz);
                sn += swz16_(sn);
                float rg = sigm_(sr);
                float zg = sigm_(sz);
                float ng = tanh_(fmaf(rg, sn, tn_));
                hj = fmaf(zg, hj - ng, ng);          // (1-z)*n + z*h
                hb[j] = hj;                          // both halves write same value
                __builtin_amdgcn_wave_barrier();
                c = c1; c1 = c2;
            }
            int b = s / 55;
            if (p == 0) atomicAdd(ws + OFF_POOL + b * 32 + (fwd ? 0 : 16) + j, hj);
            if (fwd && q == 0) atomicAdd(ws + OFF_CNT + b, 1.f);
        }
    } else {
        // ---- class RNN: 16 lanes per sample (weights fit easily: 16/lane) ----
        int grp = tid >> 4, j = tid & 15;
        float* hb = smem + 6272 + (grp << 4);
        for (int i = tid; i < 19 * 16; i += 256) {
            int o = i >> 4, jj = i & 15;
            int c = d_MAP[o];
            float v = rbih[jj] + rbhh[jj];
            #pragma unroll
            for (int d = 0; d < 16; ++d)
                v = fmaf(rWih[jj * 16 + d], emb[c * 16 + d], v);
            ldsT[o * 20 + jj] = v;                 // T2, pitch 20
        }
        f2 wv[8];
        #pragma unroll
        for (int k = 0; k < 4; ++k) {
            float4 a = *(const float4*)&rWhh[j * 16 + 4 * k];
            wv[2*k] = mkf2(a.x, a.y);  wv[2*k+1] = mkf2(a.z, a.w);
        }
        __syncthreads();

        int smp = (bi - 14080) * 16 + grp;
        const int* op = oclass + (long)smp * 55;
        int cnt = 0;
        #pragma unroll
        for (int k = 0; k < 4; ++k) {
            int pgt = j + 16 * k;
            cnt += (pgt < 55 && op[pgt] != 18);
        }
        cnt += __builtin_amdgcn_ds_swizzle(cnt, (1 << 10) | 0x1f);
        cnt += __builtin_amdgcn_ds_swizzle(cnt, (2 << 10) | 0x1f);
        cnt += __builtin_amdgcn_ds_swizzle(cnt, (4 << 10) | 0x1f);
        cnt += __builtin_amdgcn_ds_swizzle(cnt, (8 << 10) | 0x1f);
        int len = cnt;

        float hj = 0.f;
        hb[j] = 0.f;
        __builtin_amdgcn_wave_barrier();
        if (len > 0) {
            int o = op[0];
            for (int t = 0; t < len; ++t) {
                int onx = (t + 1 < len) ? op[t + 1] : 0;
                f2 a2 = mkf2(ldsT[o * 20 + j], 0.f);
                #pragma unroll
                for (int k = 0; k < 4; ++k) {
                    float4 h4 = *(const float4*)&hb[4 * k];
                    a2 = __builtin_elementwise_fma(wv[2*k],   mkf2(h4.x, h4.y), a2);
                    a2 = __builtin_elementwise_fma(wv[2*k+1], mkf2(h4.z, h4.w), a2);
                }
                hj = tanh_(a2.x + a2.y);
                hb[j] = hj;
                __builtin_amdgcn_wave_barrier();
                o = onx;
            }
        }
        ws[OFF_HC + smp * 16 + j] = hj;
    }
}

// ---------------- k3: fusion MLP (f32 in/out), conditional diagnostic
__global__ void k3_fuse(const float* fW1, const float* fb1,
                        const float* fW2, const float* fb2,
                        float* ws, float* out)
{
    int b = blockIdx.x * 256 + threadIdx.x;
    if (b >= B_) return;
    float inv = 1.f / (ws[OFF_CNT + b] + 1e-8f);
    float comb[48];
    #pragma unroll
    for (int j = 0; j < 16; ++j) comb[j] = ws[OFF_HC + b * 16 + j];
    #pragma unroll
    for (int j = 0; j < 32; ++j) comb[16 + j] = ws[OFF_POOL + b * 32 + j] * inv;

    float hid[16];
    #pragma unroll
    for (int o = 0; o < 16; ++o) {
        float v = fb1[o];
        #pragma unroll
        for (int i = 0; i < 48; ++i) v = fmaf(fW1[o * 48 + i], comb[i], v);
        hid[o] = v > 0.f ? v : 0.f;
    }
    #pragma unroll
    for (int o = 0; o < 24; ++o) {
        float v = fb2[o];
        #pragma unroll
        for (int i = 0; i < 16; ++i) v = fmaf(fW2[o * 16 + i], hid[i], v);
        out[b * 24 + o] = v;
    }

    if (b == 0) {   // silent on success
        int bb = 0;
        if (!badf(ws[OFF_POOL]))    bb |= 1;
        if (!badf(ws[OFF_HC]))      bb |= 2;
        if (ws[OFF_CNT] > 0.5f)     bb |= 4;
        if (bb != 7) {
            float code = 16384.f + 128.f * (float)bb;
            #pragma unroll
            for (int i = 4; i < 12; ++i) out[i] = code;
        }
    }
}

// ------------------------------------------------------------------- launch
extern "C" void kernel_launch(void* const* d_in, const int* in_sizes, int n_in,
                              void* d_out, int out_size, void* d_ws, size_t ws_size,
                              hipStream_t stream)
{
    const int*   oclass = (const int*)d_in[0];
    const int*   strs   = (const int*)d_in[1];
    const float* emb    = (const float*)d_in[2];
    const float* rWih   = (const float*)d_in[3];
    const float* rWhh   = (const float*)d_in[4];
    const float* rbih   = (const float*)d_in[5];
    const float* rbhh   = (const float*)d_in[6];
    const float* gWihF  = (const float*)d_in[7];
    const float* gWhhF  = (const float*)d_in[8];
    const float* gbihF  = (const float*)d_in[9];
    const float* gbhhF  = (const float*)d_in[10];
    const float* gWihB  = (const float*)d_in[11];
    const float* gWhhB  = (const float*)d_in[12];
    const float* gbihB  = (const float*)d_in[13];
    const float* gbhhB  = (const float*)d_in[14];
    const float* fW1    = (const float*)d_in[15];
    const float* fb1    = (const float*)d_in[16];
    const float* fW2    = (const float*)d_in[17];
    const float* fb2    = (const float*)d_in[18];

    float* ws  = (float*)d_ws;
    float* out = (float*)d_out;

    hipMemsetAsync(d_ws, 0, 33792 * sizeof(float), stream);

    k0_tables<<<48, 256, 0, stream>>>(emb, gWihF, gbihF, gbhhF,
                                      gWihB, gbihB, gbhhB, ws);
    k12_main<<<NTOT, 256, 0, stream>>>(oclass, strs, emb,
                                       gWhhF, gbhhF, gWhhB, gbhhB,
                                       rWih, rWhh, rbih, rbhh, ws, out);
    k3_fuse<<<4, 256, 0, stream>>>(fW1, fb1, fW2, fb2, ws, out);
}

// Round 5
// 677.883 us; speedup vs baseline: 1.6563x; 1.6563x over previous
//
#include <hip/hip_runtime.h>
#include <hip/hip_bf16.h>
#include <math.h>

#define B_     1024
#define VOCAB_ 130
#define EOS_   129

// Output FLOAT32 element offsets:
//   inv_features @0 (24576) | inv_class_emb @24576 (901120) | str_emb @925696
#define OUT_CLS_F  24576
#define OUT_STR_F  925696

// Workspace (float offsets): POOL 1024*32 | CNT 1024 | HC 1024*16 | T 2*128*48
#define OFF_POOL 0
#define OFF_CNT  32768
#define OFF_HC   33792
#define OFF_T    50176

// merged-grid geometry: 7104 k2-role blocks interleaved 1:2 with 14960 k1-role
#define NK2      7104
#define NK1      14960
#define NINT     21312          // 3 * NK2: interleaved prefix
#define NTOT     22064

typedef float f2 __attribute__((ext_vector_type(2)));

static __device__ const int d_MAP[19] =
    {128,93,41,91,61,34,40,37,33,63,43,47,36,42,96,48,95,46,128};

__device__ __forceinline__ float sigm_(float x){
    return __builtin_amdgcn_rcpf(1.f + __builtin_amdgcn_exp2f(-1.4426950408889634f * x));
}
__device__ __forceinline__ float tanh_(float x){
    return 2.f * __builtin_amdgcn_rcpf(1.f + __builtin_amdgcn_exp2f(-2.8853900817779268f * x)) - 1.f;
}
__device__ __forceinline__ int badf(float v) {
    return (v != v) || (fabsf(v) > 1e30f);
}
__device__ __forceinline__ f2 mkf2(float a, float b){ f2 r; r.x = a; r.y = b; return r; }

// ---------------- k0: precompute gi tables T[dir][c][j] = Wih_j . emb[c] + bih[j] (+bhh[j] for j<32)
__global__ void k0_tables(const float* __restrict__ emb,
                          const float* __restrict__ WihF, const float* __restrict__ bihF,
                          const float* __restrict__ bhhF,
                          const float* __restrict__ WihB, const float* __restrict__ bihB,
                          const float* __restrict__ bhhB, float* ws)
{
    int i = blockIdx.x * 256 + threadIdx.x;
    if (i >= 12288) return;                 // 2 * 128 * 48
    int dir = i / 6144, r = i - dir * 6144;
    int c = r / 48, j = r - c * 48;
    const float* Wih = dir ? WihB : WihF;
    const float* bih = dir ? bihB : bihF;
    const float* bhh = dir ? bhhB : bhhF;
    float v = bih[j] + ((j < 32) ? bhh[j] : 0.f);
    if (c != 0) {                           // padding_idx=0 -> emb row 0 is zero
        const float* e = emb + c * 16;
        #pragma unroll
        for (int d = 0; d < 16; ++d) v = fmaf(Wih[j * 16 + d], e[d], v);
    }
    ws[OFF_T + i] = v;
}

// ---------------- k12: merged embed-gather (k1 role) + GRU/RNN (k2 role)
// role by block index: bi<21312: bi%3==0 -> k2(bi/3), else k1(bi - bi/3 - 1);
//                      bi>=21312: k1(14208 + bi - 21312)
// LDS union (2920 floats = 11680 B):
//   k1 : [0,2600) embF(pitch20) | [2600,2920) chs
//   GRU: [0,256) h-exchange (16 groups x 16)  -- T table read from global/L2
//   cls: [0,380) T2(pitch20)   | [400,656) h-exchange
__global__ __launch_bounds__(256)
__attribute__((amdgpu_waves_per_eu(1, 5)))
void k12_main(const int* oclass, const int* strs, const float* __restrict__ emb,
              const float* __restrict__ WhhF, const float* __restrict__ bhhF,
              const float* __restrict__ WhhB, const float* __restrict__ bhhB,
              const float* __restrict__ rWih, const float* __restrict__ rWhh,
              const float* __restrict__ rbih, const float* __restrict__ rbhh,
              float* ws, float* out)
{
    __shared__ __align__(16) float smem[2920];       // 11680 B union
    int bi0 = blockIdx.x, tid = threadIdx.x;

    int k2id = -1, k1id;
    if (bi0 < NINT) {
        if (bi0 % 3 == 0) k2id = bi0 / 3;
        else              k1id = bi0 - bi0 / 3 - 1;
    } else {
        k1id = 14208 + (bi0 - NINT);
    }

    if (k2id < 0) {
        // ================= k1 role: f32 gathers (str_emb + EOS, inv_class_emb)
        float* embF = smem;                          // pitch 20
        int*   chs  = (int*)(smem + 2600);           // 4 * 80
        for (int i = tid; i < VOCAB_ * 16; i += 256) {
            int r = i >> 4, c = i & 15;
            embF[r * 20 + c] = (r == 0) ? 0.f : emb[i];   // padding_idx=0
        }
        __syncthreads();

        if (k1id < 14080) {
            int w = tid >> 6, lane = tid & 63;
            int s = k1id * 4 + w;
            const int* cp = strs + (long)s * 80;
            int ca = cp[lane];
            int cb = (lane < 16) ? cp[64 + lane] : 0;
            unsigned long long m1 = __ballot(ca != 0);
            unsigned long long m2 = __ballot((lane < 16) && (cb != 0));
            int L = __popcll(m1) + __popcll(m2);
            if (lane == L) ca = EOS_;
            if (lane < 16 && (64 + lane) == L) cb = EOS_;
            chs[w * 80 + lane] = ca;                 // wave-local slice: no barrier
            if (lane < 16) chs[w * 80 + 64 + lane] = cb;
            float4* dst = (float4*)(out + OUT_STR_F + (long)s * 1280);
            #pragma unroll
            for (int it = 0; it < 5; ++it) {
                int q = it * 64 + lane;
                int row = q >> 2, part = q & 3;
                int ch = chs[w * 80 + row];
                dst[q] = *(const float4*)&embF[ch * 20 + part * 4];
            }
        } else {
            int q = (k1id - 14080) * 256 + tid;
            int bs = q >> 2, part = q & 3;
            int c = d_MAP[oclass[bs]];
            float4* dst = (float4*)(out + OUT_CLS_F);
            dst[q] = *(const float4*)&embF[c * 20 + part * 4];
        }
        return;
    }

    // ================= k2 role
    int bi = k2id;
    int grp = tid >> 4, j = tid & 15;

    if (bi < 7040) {
        // ---- GRU: 16 lanes per sequence; weights resident in VGPRs (volatile load)
        float* hb = smem + (grp << 4);
        bool fwd = bi < 3520;
        const float* Whh = fwd ? WhhF : WhhB;
        const float* bhh = fwd ? bhhF : bhhB;
        const float* Tg  = ws + OFF_T + (fwd ? 0 : 6144);   // L2-hot gi-table

        // volatile weight loads: compiler cannot rematerialize -> stays in VGPRs
        float wv_[48];
        {
            volatile const float* vp0 = Whh + j * 16;
            volatile const float* vp1 = Whh + 256 + j * 16;
            volatile const float* vp2 = Whh + 512 + j * 16;
            #pragma unroll
            for (int d = 0; d < 16; ++d) wv_[d]      = vp0[d];
            #pragma unroll
            for (int d = 0; d < 16; ++d) wv_[16 + d] = vp1[d];
            #pragma unroll
            for (int d = 0; d < 16; ++d) wv_[32 + d] = vp2[d];
        }
        f2 wr[8], wz[8], wn[8];
        #pragma unroll
        for (int k = 0; k < 8; ++k) {
            wr[k] = mkf2(wv_[2*k],      wv_[2*k + 1]);
            wz[k] = mkf2(wv_[16 + 2*k], wv_[16 + 2*k + 1]);
            wn[k] = mkf2(wv_[32 + 2*k], wv_[32 + 2*k + 1]);
        }
        #pragma unroll
        for (int k = 0; k < 8; ++k) {
            asm volatile("" : "+v"(wr[k]));
            asm volatile("" : "+v"(wz[k]));
            asm volatile("" : "+v"(wn[k]));
        }
        float bn = bhh[32 + j];

        int s = (fwd ? bi : bi - 3520) * 16 + grp;
        const int* cp = strs + (long)s * 80;

        // group-parallel length: lane j counts positions j+16k, swizzle-reduce
        int cnt = 0;
        #pragma unroll
        for (int k = 0; k < 5; ++k) cnt += (cp[j + 16 * k] != 0);
        cnt += __builtin_amdgcn_ds_swizzle(cnt, (1 << 10) | 0x1f);
        cnt += __builtin_amdgcn_ds_swizzle(cnt, (2 << 10) | 0x1f);
        cnt += __builtin_amdgcn_ds_swizzle(cnt, (4 << 10) | 0x1f);
        cnt += __builtin_amdgcn_ds_swizzle(cnt, (8 << 10) | 0x1f);
        int L = cnt;

        float hj = 0.f;
        hb[j] = 0.f;
        __builtin_amdgcn_wave_barrier();
        if (L > 0) {
            int base = fwd ? 0 : (L - 1);
            int stp  = fwd ? 1 : -1;
            int c0 = cp[base];
            int c1 = (L > 1) ? cp[base + stp] : 0;
            int c2 = (L > 2) ? cp[base + 2 * stp] : 0;
            // T-row register prefetch, 2 steps deep (L2 latency ~200cy < 2 steps)
            const float* rA = Tg + c0 * 48 + j;
            float tA0 = rA[0], tA1 = rA[16], tA2 = rA[32];
            const float* rB = Tg + c1 * 48 + j;
            float tB0 = rB[0], tB1 = rB[16], tB2 = rB[32];
            for (int t = 0; t < L; ++t) {
                int c3 = (t + 3 < L) ? cp[base + (t + 3) * stp] : 0;
                const float* rC = Tg + c2 * 48 + j;     // issue prefetch for t+2
                float tC0 = rC[0], tC1 = rC[16], tC2 = rC[32];
                f2 ar = mkf2(tA0, 0.f);
                f2 az = mkf2(tA1, 0.f);
                f2 an = mkf2(bn, 0.f);     // T_n stays out: r scales only W_n.h + b_n
                float4 h0 = *(const float4*)&hb[0];
                float4 h1 = *(const float4*)&hb[4];
                float4 h2 = *(const float4*)&hb[8];
                float4 h3 = *(const float4*)&hb[12];
                f2 ha = mkf2(h0.x, h0.y), hbv = mkf2(h0.z, h0.w);
                f2 hc = mkf2(h1.x, h1.y), hd  = mkf2(h1.z, h1.w);
                f2 he = mkf2(h2.x, h2.y), hf  = mkf2(h2.z, h2.w);
                f2 hg = mkf2(h3.x, h3.y), hh  = mkf2(h3.z, h3.w);
                ar = __builtin_elementwise_fma(wr[0], ha,  ar);
                az = __builtin_elementwise_fma(wz[0], ha,  az);
                an = __builtin_elementwise_fma(wn[0], ha,  an);
                ar = __builtin_elementwise_fma(wr[1], hbv, ar);
                az = __builtin_elementwise_fma(wz[1], hbv, az);
                an = __builtin_elementwise_fma(wn[1], hbv, an);
                ar = __builtin_elementwise_fma(wr[2], hc,  ar);
                az = __builtin_elementwise_fma(wz[2], hc,  az);
                an = __builtin_elementwise_fma(wn[2], hc,  an);
                ar = __builtin_elementwise_fma(wr[3], hd,  ar);
                az = __builtin_elementwise_fma(wz[3], hd,  az);
                an = __builtin_elementwise_fma(wn[3], hd,  an);
                ar = __builtin_elementwise_fma(wr[4], he,  ar);
                az = __builtin_elementwise_fma(wz[4], he,  az);
                an = __builtin_elementwise_fma(wn[4], he,  an);
                ar = __builtin_elementwise_fma(wr[5], hf,  ar);
                az = __builtin_elementwise_fma(wz[5], hf,  az);
                an = __builtin_elementwise_fma(wn[5], hf,  an);
                ar = __builtin_elementwise_fma(wr[6], hg,  ar);
                az = __builtin_elementwise_fma(wz[6], hg,  az);
                an = __builtin_elementwise_fma(wn[6], hg,  an);
                ar = __builtin_elementwise_fma(wr[7], hh,  ar);
                az = __builtin_elementwise_fma(wz[7], hh,  az);
                an = __builtin_elementwise_fma(wn[7], hh,  an);
                float rg = sigm_(ar.x + ar.y);
                float zg = sigm_(az.x + az.y);
                float ng = tanh_(fmaf(rg, an.x + an.y, tA2));
                hj = fmaf(zg, hj - ng, ng);          // (1-z)*n + z*h
                hb[j] = hj;                          // publish for next step
                __builtin_amdgcn_wave_barrier();     // pin write before next-iter reads
                tA0 = tB0; tA1 = tB1; tA2 = tB2;
                tB0 = tC0; tB1 = tC1; tB2 = tC2;
                c2 = c3;
            }
            int b = s / 55;
            atomicAdd(ws + OFF_POOL + b * 32 + (fwd ? 0 : 16) + j, hj);
            if (fwd && j == 0) atomicAdd(ws + OFF_CNT + b, 1.f);
        }
    } else {
        // ---- class RNN: 16 lanes per sample ----
        float* ldsT = smem;                          // T2, pitch 20 (380 floats)
        float* hb   = smem + 400 + (grp << 4);
        for (int i = tid; i < 19 * 16; i += 256) {
            int o = i >> 4, jj = i & 15;
            int c = d_MAP[o];
            float v = rbih[jj] + rbhh[jj];
            #pragma unroll
            for (int d = 0; d < 16; ++d)
                v = fmaf(rWih[jj * 16 + d], emb[c * 16 + d], v);
            ldsT[o * 20 + jj] = v;
        }
        f2 wv[8];
        #pragma unroll
        for (int k = 0; k < 4; ++k) {
            float4 a = *(const float4*)&rWhh[j * 16 + 4 * k];
            wv[2*k] = mkf2(a.x, a.y);  wv[2*k+1] = mkf2(a.z, a.w);
        }
        __syncthreads();

        int smp = (bi - 7040) * 16 + grp;
        const int* op = oclass + (long)smp * 55;
        int cnt = 0;
        #pragma unroll
        for (int k = 0; k < 4; ++k) {
            int pgt = j + 16 * k;
            cnt += (pgt < 55 && op[pgt] != 18);
        }
        cnt += __builtin_amdgcn_ds_swizzle(cnt, (1 << 10) | 0x1f);
        cnt += __builtin_amdgcn_ds_swizzle(cnt, (2 << 10) | 0x1f);
        cnt += __builtin_amdgcn_ds_swizzle(cnt, (4 << 10) | 0x1f);
        cnt += __builtin_amdgcn_ds_swizzle(cnt, (8 << 10) | 0x1f);
        int len = cnt;

        float hj = 0.f;
        hb[j] = 0.f;
        __builtin_amdgcn_wave_barrier();
        if (len > 0) {
            int o = op[0];
            for (int t = 0; t < len; ++t) {
                int onx = (t + 1 < len) ? op[t + 1] : 0;
                f2 a2 = mkf2(ldsT[o * 20 + j], 0.f);
                #pragma unroll
                for (int k = 0; k < 4; ++k) {
                    float4 h4 = *(const float4*)&hb[4 * k];
                    a2 = __builtin_elementwise_fma(wv[2*k],   mkf2(h4.x, h4.y), a2);
                    a2 = __builtin_elementwise_fma(wv[2*k+1], mkf2(h4.z, h4.w), a2);
                }
                hj = tanh_(a2.x + a2.y);
                hb[j] = hj;
                __builtin_amdgcn_wave_barrier();
                o = onx;
            }
        }
        ws[OFF_HC + smp * 16 + j] = hj;
    }
}

// ---------------- k3: fusion MLP (f32 in/out), conditional diagnostic
__global__ void k3_fuse(const float* fW1, const float* fb1,
                        const float* fW2, const float* fb2,
                        float* ws, float* out)
{
    int b = blockIdx.x * 256 + threadIdx.x;
    if (b >= B_) return;
    float inv = 1.f / (ws[OFF_CNT + b] + 1e-8f);
    float comb[48];
    #pragma unroll
    for (int j = 0; j < 16; ++j) comb[j] = ws[OFF_HC + b * 16 + j];
    #pragma unroll
    for (int j = 0; j < 32; ++j) comb[16 + j] = ws[OFF_POOL + b * 32 + j] * inv;

    float hid[16];
    #pragma unroll
    for (int o = 0; o < 16; ++o) {
        float v = fb1[o];
        #pragma unroll
        for (int i = 0; i < 48; ++i) v = fmaf(fW1[o * 48 + i], comb[i], v);
        hid[o] = v > 0.f ? v : 0.f;
    }
    #pragma unroll
    for (int o = 0; o < 24; ++o) {
        float v = fb2[o];
        #pragma unroll
        for (int i = 0; i < 16; ++i) v = fmaf(fW2[o * 16 + i], hid[i], v);
        out[b * 24 + o] = v;
    }

    if (b == 0) {   // silent on success
        int bb = 0;
        if (!badf(ws[OFF_POOL]))    bb |= 1;
        if (!badf(ws[OFF_HC]))      bb |= 2;
        if (ws[OFF_CNT] > 0.5f)     bb |= 4;
        if (bb != 7) {
            float code = 16384.f + 128.f * (float)bb;
            #pragma unroll
            for (int i = 4; i < 12; ++i) out[i] = code;
        }
    }
}

// ------------------------------------------------------------------- launch
extern "C" void kernel_launch(void* const* d_in, const int* in_sizes, int n_in,
                              void* d_out, int out_size, void* d_ws, size_t ws_size,
                              hipStream_t stream)
{
    const int*   oclass = (const int*)d_in[0];
    const int*   strs   = (const int*)d_in[1];
    const float* emb    = (const float*)d_in[2];
    const float* rWih   = (const float*)d_in[3];
    const float* rWhh   = (const float*)d_in[4];
    const float* rbih   = (const float*)d_in[5];
    const float* rbhh   = (const float*)d_in[6];
    const float* gWihF  = (const float*)d_in[7];
    const float* gWhhF  = (const float*)d_in[8];
    const float* gbihF  = (const float*)d_in[9];
    const float* gbhhF  = (const float*)d_in[10];
    const float* gWihB  = (const float*)d_in[11];
    const float* gWhhB  = (const float*)d_in[12];
    const float* gbihB  = (const float*)d_in[13];
    const float* gbhhB  = (const float*)d_in[14];
    const float* fW1    = (const float*)d_in[15];
    const float* fb1    = (const float*)d_in[16];
    const float* fW2    = (const float*)d_in[17];
    const float* fb2    = (const float*)d_in[18];

    float* ws  = (float*)d_ws;
    float* out = (float*)d_out;

    hipMemsetAsync(d_ws, 0, 33792 * sizeof(float), stream);

    k0_tables<<<48, 256, 0, stream>>>(emb, gWihF, gbihF, gbhhF,
                                      gWihB, gbihB, gbhhB, ws);
    k12_main<<<NTOT, 256, 0, stream>>>(oclass, strs, emb,
                                       gWhhF, gbhhF, gWhhB, gbhhB,
                                       rWih, rWhh, rbih, rbhh, ws, out);
    k3_fuse<<<4, 256, 0, stream>>>(fW1, fb1, fW2, fb2, ws, out);
}

// Round 6
// 664.978 us; speedup vs baseline: 1.6884x; 1.0194x over previous
//
#include <hip/hip_runtime.h>
#include <hip/hip_bf16.h>
#include <math.h>

#define B_     1024
#define VOCAB_ 130
#define EOS_   129

// Output FLOAT32 element offsets:
//   inv_features @0 (24576) | inv_class_emb @24576 (901120) | str_emb @925696
#define OUT_CLS_F  24576
#define OUT_STR_F  925696

// Workspace (float offsets): POOL 1024*32 | CNT 1024 | HC 1024*16 | T 2*128*48
#define OFF_POOL 0
#define OFF_CNT  32768
#define OFF_HC   33792
#define OFF_T    50176

// merged-grid geometry: 7104 k2-role blocks interleaved 1:2 with 14960 k1-role
#define NK2      7104
#define NK1      14960
#define NINT     21312          // 3 * NK2: interleaved prefix
#define NTOT     22064

static __device__ const int d_MAP[19] =
    {128,93,41,91,61,34,40,37,33,63,43,47,36,42,96,48,95,46,128};

__device__ __forceinline__ float sigm_(float x){
    return __builtin_amdgcn_rcpf(1.f + __builtin_amdgcn_exp2f(-1.4426950408889634f * x));
}
__device__ __forceinline__ float tanh_(float x){
    return 2.f * __builtin_amdgcn_rcpf(1.f + __builtin_amdgcn_exp2f(-2.8853900817779268f * x)) - 1.f;
}
__device__ __forceinline__ int badf(float v) {
    return (v != v) || (fabsf(v) > 1e30f);
}

// ---------------- k0: precompute gi tables T[dir][c][j] = Wih_j . emb[c] + bih[j] (+bhh[j] for j<32)
__global__ void k0_tables(const float* __restrict__ emb,
                          const float* __restrict__ WihF, const float* __restrict__ bihF,
                          const float* __restrict__ bhhF,
                          const float* __restrict__ WihB, const float* __restrict__ bihB,
                          const float* __restrict__ bhhB, float* ws)
{
    int i = blockIdx.x * 256 + threadIdx.x;
    if (i >= 12288) return;                 // 2 * 128 * 48
    int dir = i / 6144, r = i - dir * 6144;
    int c = r / 48, j = r - c * 48;
    const float* Wih = dir ? WihB : WihF;
    const float* bih = dir ? bihB : bihF;
    const float* bhh = dir ? bhhB : bhhF;
    float v = bih[j] + ((j < 32) ? bhh[j] : 0.f);
    if (c != 0) {                           // padding_idx=0 -> emb row 0 is zero
        const float* e = emb + c * 16;
        #pragma unroll
        for (int d = 0; d < 16; ++d) v = fmaf(Wih[j * 16 + d], e[d], v);
    }
    ws[OFF_T + i] = v;
}

// ---------------- k12: merged embed-gather (k1 role) + GRU/RNN (k2 role)
// role by block index: bi<21312: bi%3==0 -> k2(bi/3), else k1(bi - bi/3 - 1);
//                      bi>=21312: k1(14208 + bi - 21312)
// LDS union (6272 floats = 25088 B):
//   k1 : [0,2600) embF(pitch20) | [2600,2920) chs
//   GRU: [0,6272) T-table(pitch49); h exchanged via ds_swizzle (no LDS)
//   cls: [0,380) T2(pitch20);      h exchanged via ds_swizzle
__global__ __launch_bounds__(256)
__attribute__((amdgpu_waves_per_eu(1, 4)))
void k12_main(const int* oclass, const int* strs, const float* __restrict__ emb,
              const float* __restrict__ WhhF, const float* __restrict__ bhhF,
              const float* __restrict__ WhhB, const float* __restrict__ bhhB,
              const float* __restrict__ rWih, const float* __restrict__ rWhh,
              const float* __restrict__ rbih, const float* __restrict__ rbhh,
              float* ws, float* out)
{
    __shared__ __align__(16) float smem[6272];       // 25088 B union
    int bi0 = blockIdx.x, tid = threadIdx.x;

    int k2id = -1, k1id;
    if (bi0 < NINT) {
        if (bi0 % 3 == 0) k2id = bi0 / 3;
        else              k1id = bi0 - bi0 / 3 - 1;
    } else {
        k1id = 14208 + (bi0 - NINT);
    }

    if (k2id < 0) {
        // ================= k1 role: f32 gathers (str_emb + EOS, inv_class_emb)
        float* embF = smem;                          // pitch 20
        int*   chs  = (int*)(smem + 2600);           // 4 * 80
        for (int i = tid; i < VOCAB_ * 16; i += 256) {
            int r = i >> 4, c = i & 15;
            embF[r * 20 + c] = (r == 0) ? 0.f : emb[i];   // padding_idx=0
        }
        __syncthreads();

        if (k1id < 14080) {
            int w = tid >> 6, lane = tid & 63;
            int s = k1id * 4 + w;
            const int* cp = strs + (long)s * 80;
            int ca = cp[lane];
            int cb = (lane < 16) ? cp[64 + lane] : 0;
            unsigned long long m1 = __ballot(ca != 0);
            unsigned long long m2 = __ballot((lane < 16) && (cb != 0));
            int L = __popcll(m1) + __popcll(m2);
            if (lane == L) ca = EOS_;
            if (lane < 16 && (64 + lane) == L) cb = EOS_;
            chs[w * 80 + lane] = ca;                 // wave-local slice: no barrier
            if (lane < 16) chs[w * 80 + 64 + lane] = cb;
            float4* dst = (float4*)(out + OUT_STR_F + (long)s * 1280);
            #pragma unroll
            for (int it = 0; it < 5; ++it) {
                int q = it * 64 + lane;
                int row = q >> 2, part = q & 3;
                int ch = chs[w * 80 + row];
                dst[q] = *(const float4*)&embF[ch * 20 + part * 4];
            }
        } else {
            int q = (k1id - 14080) * 256 + tid;
            int bs = q >> 2, part = q & 3;
            int c = d_MAP[oclass[bs]];
            float4* dst = (float4*)(out + OUT_CLS_F);
            dst[q] = *(const float4*)&embF[c * 20 + part * 4];
        }
        return;
    }

    // ================= k2 role
    int bi = k2id;
    int grp = tid >> 4, j = tid & 15;
    float* ldsT = smem;

    if (bi < 7040) {
        // ---- GRU: 16 lanes per sequence; h exchange via xor-swizzle (no LDS, no barrier)
        bool fwd = bi < 3520;
        const float* __restrict__ Whh = fwd ? WhhF : WhhB;
        const float* __restrict__ bhh = fwd ? bhhF : bhhB;

        // stage gi-table [128][48] -> LDS pitch 49
        const float* Tg = ws + OFF_T + (fwd ? 0 : 6144);
        for (int i = tid; i < 6144; i += 256) {
            int c = i / 48, qq = i - c * 48;
            ldsT[c * 49 + qq] = Tg[i];
        }

        // per-lane weights in swizzle order: w*[r] = W_gate[j][j^r]
        float wr_[16], wz_[16], wn_[16];
        #pragma unroll
        for (int r = 0; r < 16; ++r) {
            int idx = j * 16 + (j ^ r);
            wr_[r] = Whh[idx];
            wz_[r] = Whh[256 + idx];
            wn_[r] = Whh[512 + idx];
        }
        float bn = bhh[32 + j];
        __syncthreads();

        int s = (fwd ? bi : bi - 3520) * 16 + grp;
        const int* cp = strs + (long)s * 80;

        // group-parallel length: lane j counts positions j+16k, swizzle-reduce
        int cnt = 0;
        #pragma unroll
        for (int k = 0; k < 5; ++k) cnt += (cp[j + 16 * k] != 0);
        cnt += __builtin_amdgcn_ds_swizzle(cnt, (1 << 10) | 0x1f);
        cnt += __builtin_amdgcn_ds_swizzle(cnt, (2 << 10) | 0x1f);
        cnt += __builtin_amdgcn_ds_swizzle(cnt, (4 << 10) | 0x1f);
        cnt += __builtin_amdgcn_ds_swizzle(cnt, (8 << 10) | 0x1f);
        int L = cnt;

        float hj = 0.f;
        if (L > 0) {
            int base = fwd ? 0 : (L - 1);
            int stp  = fwd ? 1 : -1;
            int c1 = (L > 1) ? cp[base + stp] : 0;        // char for t+1
            int c2 = (L > 2) ? cp[base + 2 * stp] : 0;    // char for t+2
            const float* Tr0 = ldsT + cp[base] * 49;
            float tC0 = Tr0[j], tC1 = Tr0[16 + j], tC2 = Tr0[32 + j];

            for (int t = 0; t < L; ++t) {
                // prefetch T-row for t+1 (consumed next iter; latency off-chain)
                const float* Trn = ldsT + c1 * 49;
                float tN0 = Trn[j], tN1 = Trn[16 + j], tN2 = Trn[32 + j];
                int c3 = (t + 3 < L) ? cp[base + (t + 3) * stp] : 0;

                // pin weights in arch VGPRs: per-iter redefinition makes
                // AGPR-parking / remat cost 2 copies per value per step
                asm volatile("" :
                    "+v"(wr_[0]), "+v"(wr_[1]), "+v"(wr_[2]),  "+v"(wr_[3]),
                    "+v"(wr_[4]), "+v"(wr_[5]), "+v"(wr_[6]),  "+v"(wr_[7]),
                    "+v"(wr_[8]), "+v"(wr_[9]), "+v"(wr_[10]), "+v"(wr_[11]),
                    "+v"(wr_[12]),"+v"(wr_[13]),"+v"(wr_[14]), "+v"(wr_[15]));
                asm volatile("" :
                    "+v"(wz_[0]), "+v"(wz_[1]), "+v"(wz_[2]),  "+v"(wz_[3]),
                    "+v"(wz_[4]), "+v"(wz_[5]), "+v"(wz_[6]),  "+v"(wz_[7]),
                    "+v"(wz_[8]), "+v"(wz_[9]), "+v"(wz_[10]), "+v"(wz_[11]),
                    "+v"(wz_[12]),"+v"(wz_[13]),"+v"(wz_[14]), "+v"(wz_[15]));
                asm volatile("" :
                    "+v"(wn_[0]), "+v"(wn_[1]), "+v"(wn_[2]),  "+v"(wn_[3]),
                    "+v"(wn_[4]), "+v"(wn_[5]), "+v"(wn_[6]),  "+v"(wn_[7]),
                    "+v"(wn_[8]), "+v"(wn_[9]), "+v"(wn_[10]), "+v"(wn_[11]),
                    "+v"(wn_[12]),"+v"(wn_[13]),"+v"(wn_[14]), "+v"(wn_[15]));

                float ar = tC0, az = tC1, an = bn;
                ar = fmaf(wr_[0], hj, ar);
                az = fmaf(wz_[0], hj, az);
                an = fmaf(wn_[0], hj, an);
                #define STEPR(r) { \
                    float hx = __int_as_float(__builtin_amdgcn_ds_swizzle( \
                        __float_as_int(hj), ((r) << 10) | 0x1f)); \
                    ar = fmaf(wr_[r], hx, ar); \
                    az = fmaf(wz_[r], hx, az); \
                    an = fmaf(wn_[r], hx, an); }
                STEPR(1)  STEPR(2)  STEPR(3)  STEPR(4)  STEPR(5)
                STEPR(6)  STEPR(7)  STEPR(8)  STEPR(9)  STEPR(10)
                STEPR(11) STEPR(12) STEPR(13) STEPR(14) STEPR(15)
                #undef STEPR

                float rg = sigm_(ar);
                float zg = sigm_(az);
                float ng = tanh_(fmaf(rg, an, tC2));   // T_n outside: r scales b_n + W_n.h
                hj = fmaf(zg, hj - ng, ng);            // (1-z)*n + z*h

                tC0 = tN0; tC1 = tN1; tC2 = tN2;
                c1 = c2; c2 = c3;
            }
            int b = s / 55;
            atomicAdd(ws + OFF_POOL + b * 32 + (fwd ? 0 : 16) + j, hj);
            if (fwd && j == 0) atomicAdd(ws + OFF_CNT + b, 1.f);
        }
    } else {
        // ---- class RNN: 16 lanes per sample, swizzle h-exchange ----
        for (int i = tid; i < 19 * 16; i += 256) {
            int o = i >> 4, jj = i & 15;
            int c = d_MAP[o];
            float v = rbih[jj] + rbhh[jj];
            #pragma unroll
            for (int d = 0; d < 16; ++d)
                v = fmaf(rWih[jj * 16 + d], emb[c * 16 + d], v);
            ldsT[o * 20 + jj] = v;                 // T2, pitch 20
        }
        float wv_[16];
        #pragma unroll
        for (int r = 0; r < 16; ++r)
            wv_[r] = rWhh[j * 16 + (j ^ r)];
        __syncthreads();

        int smp = (bi - 7040) * 16 + grp;
        const int* op = oclass + (long)smp * 55;
        int cnt = 0;
        #pragma unroll
        for (int k = 0; k < 4; ++k) {
            int pgt = j + 16 * k;
            cnt += (pgt < 55 && op[pgt] != 18);
        }
        cnt += __builtin_amdgcn_ds_swizzle(cnt, (1 << 10) | 0x1f);
        cnt += __builtin_amdgcn_ds_swizzle(cnt, (2 << 10) | 0x1f);
        cnt += __builtin_amdgcn_ds_swizzle(cnt, (4 << 10) | 0x1f);
        cnt += __builtin_amdgcn_ds_swizzle(cnt, (8 << 10) | 0x1f);
        int len = cnt;

        float hj = 0.f;
        if (len > 0) {
            int o = op[0];
            for (int t = 0; t < len; ++t) {
                int onx = (t + 1 < len) ? op[t + 1] : 0;
                float a = ldsT[o * 20 + j];
                a = fmaf(wv_[0], hj, a);
                #define CSTEP(r) { \
                    float hx = __int_as_float(__builtin_amdgcn_ds_swizzle( \
                        __float_as_int(hj), ((r) << 10) | 0x1f)); \
                    a = fmaf(wv_[r], hx, a); }
                CSTEP(1)  CSTEP(2)  CSTEP(3)  CSTEP(4)  CSTEP(5)
                CSTEP(6)  CSTEP(7)  CSTEP(8)  CSTEP(9)  CSTEP(10)
                CSTEP(11) CSTEP(12) CSTEP(13) CSTEP(14) CSTEP(15)
                #undef CSTEP
                hj = tanh_(a);
                o = onx;
            }
        }
        ws[OFF_HC + smp * 16 + j] = hj;
    }
}

// ---------------- k3: fusion MLP (f32 in/out), conditional diagnostic
__global__ void k3_fuse(const float* fW1, const float* fb1,
                        const float* fW2, const float* fb2,
                        float* ws, float* out)
{
    int b = blockIdx.x * 256 + threadIdx.x;
    if (b >= B_) return;
    float inv = 1.f / (ws[OFF_CNT + b] + 1e-8f);
    float comb[48];
    #pragma unroll
    for (int j = 0; j < 16; ++j) comb[j] = ws[OFF_HC + b * 16 + j];
    #pragma unroll
    for (int j = 0; j < 32; ++j) comb[16 + j] = ws[OFF_POOL + b * 32 + j] * inv;

    float hid[16];
    #pragma unroll
    for (int o = 0; o < 16; ++o) {
        float v = fb1[o];
        #pragma unroll
        for (int i = 0; i < 48; ++i) v = fmaf(fW1[o * 48 + i], comb[i], v);
        hid[o] = v > 0.f ? v : 0.f;
    }
    #pragma unroll
    for (int o = 0; o < 24; ++o) {
        float v = fb2[o];
        #pragma unroll
        for (int i = 0; i < 16; ++i) v = fmaf(fW2[o * 16 + i], hid[i], v);
        out[b * 24 + o] = v;
    }

    if (b == 0) {   // silent on success
        int bb = 0;
        if (!badf(ws[OFF_POOL]))    bb |= 1;
        if (!badf(ws[OFF_HC]))      bb |= 2;
        if (ws[OFF_CNT] > 0.5f)     bb |= 4;
        if (bb != 7) {
            float code = 16384.f + 128.f * (float)bb;
            #pragma unroll
            for (int i = 4; i < 12; ++i) out[i] = code;
        }
    }
}

// ------------------------------------------------------------------- launch
extern "C" void kernel_launch(void* const* d_in, const int* in_sizes, int n_in,
                              void* d_out, int out_size, void* d_ws, size_t ws_size,
                              hipStream_t stream)
{
    const int*   oclass = (const int*)d_in[0];
    const int*   strs   = (const int*)d_in[1];
    const float* emb    = (const float*)d_in[2];
    const float* rWih   = (const float*)d_in[3];
    const float* rWhh   = (const float*)d_in[4];
    const float* rbih   = (const float*)d_in[5];
    const float* rbhh   = (const float*)d_in[6];
    const float* gWihF  = (const float*)d_in[7];
    const float* gWhhF  = (const float*)d_in[8];
    const float* gbihF  = (const float*)d_in[9];
    const float* gbhhF  = (const float*)d_in[10];
    const float* gWihB  = (const float*)d_in[11];
    const float* gWhhB  = (const float*)d_in[12];
    const float* gbihB  = (const float*)d_in[13];
    const float* gbhhB  = (const float*)d_in[14];
    const float* fW1    = (const float*)d_in[15];
    const float* fb1    = (const float*)d_in[16];
    const float* fW2    = (const float*)d_in[17];
    const float* fb2    = (const float*)d_in[18];

    float* ws  = (float*)d_ws;
    float* out = (float*)d_out;

    hipMemsetAsync(d_ws, 0, 33792 * sizeof(float), stream);

    k0_tables<<<48, 256, 0, stream>>>(emb, gWihF, gbihF, gbhhF,
                                      gWihB, gbihB, gbhhB, ws);
    k12_main<<<NTOT, 256, 0, stream>>>(oclass, strs, emb,
                                       gWhhF, gbhhF, gWhhB, gbhhB,
                                       rWih, rWhh, rbih, rbhh, ws, out);
    k3_fuse<<<4, 256, 0, stream>>>(fW1, fb1, fW2, fb2, ws, out);
}